// Round 1
// baseline (1497.605 us; speedup 1.0000x reference)
//
#include <hip/hip_runtime.h>

typedef unsigned short u16;
typedef __attribute__((ext_vector_type(8))) short short8;
typedef __attribute__((ext_vector_type(4))) short short4v;
typedef __attribute__((ext_vector_type(4))) float f32x4;

// ---- packed-weight offsets in d_ws (u16 elements) ----
static constexpr int WP2_O   = 0;
static constexpr int WP4_O   = 16384;
static constexpr int WUP_O   = 32768;
static constexpr int WDOWN_O = 40960;
static constexpr int WSBF_O  = 49152;
static constexpr int WSBF1_O = 57344;
static constexpr int WSBF2_O = 58368;
static constexpr int RB1_O   = 62464;
static constexpr int RB2_O   = 78848;
static constexpr int WLIN_O  = 95232;
static constexpr int RA10_O  = 111616;
static constexpr int RA20_O  = 128000;
static constexpr int RA11_O  = 144384;
static constexpr int RA21_O  = 160768;
static constexpr long XP4D_O = 180224;      // bf16 [E][64]
static constexpr long TAP_O  = 25780224;    // bf16 [E][64]

static __device__ __forceinline__ float bf2f(u16 u){
  union { unsigned i; float f; } v; v.i = ((unsigned)u) << 16; return v.f;
}
static __device__ __forceinline__ u16 f2bf(float f){
  union { float f; unsigned i; } v; v.f = f;
  unsigned r = v.i + 0x7FFFu + ((v.i >> 16) & 1u);
  return (u16)(r >> 16);
}
static __device__ __forceinline__ void silu4(f32x4 &v){
  #pragma unroll
  for (int m = 0; m < 4; ++m) v[m] = v[m] / (1.f + __expf(-v[m]));
}
static __device__ __forceinline__ f32x4 mfma_(short8 a, short8 b, f32x4 c){
  return __builtin_amdgcn_mfma_f32_16x16x32_bf16(a, b, c, 0, 0, 0);
}
// activation LDS layout: row e = 128 u16 (256B), 16B blocks XOR-swizzled by (e&15)
static __device__ __forceinline__ void store_pack(u16* dst, int e, int n0, f32x4 v){
  int phys = ((n0 >> 3) ^ (e & 15));
  short4v s;
  s[0] = (short)f2bf(v[0]); s[1] = (short)f2bf(v[1]);
  s[2] = (short)f2bf(v[2]); s[3] = (short)f2bf(v[3]);
  *(short4v*)(dst + e*128 + phys*8 + (n0 & 7)) = s;
}
static __device__ __forceinline__ f32x4 load_pack(const u16* src, int e, int n0){
  int phys = ((n0 >> 3) ^ (e & 15));
  short4v s = *(const short4v*)(src + e*128 + phys*8 + (n0 & 7));
  f32x4 v;
  v[0] = bf2f((u16)s[0]); v[1] = bf2f((u16)s[1]);
  v[2] = bf2f((u16)s[2]); v[3] = bf2f((u16)s[3]);
  return v;
}
static __device__ __forceinline__ void zero44(f32x4 a[4][4]){
  #pragma unroll
  for (int i = 0; i < 4; ++i)
    #pragma unroll
    for (int j = 0; j < 4; ++j)
      a[i][j] = (f32x4){0.f,0.f,0.f,0.f};
}

// GEMM: D[n][e] += W[n][k]*act[e][k]; wave (nhalf,ehalf) covers 64n x 64e (4x4 16-tiles)
// A-frags from packed global weights; B-frags from swizzled LDS activation.
template<int KS>
static __device__ __forceinline__ void gemm44(const u16* __restrict__ wp, const u16* act,
                                              int lane, int nhalf, int ehalf, f32x4 acc[4][4]){
  const int l15 = lane & 15, q = lane >> 4;
  #pragma unroll
  for (int ks = 0; ks < KS; ++ks){
    short8 a[4];
    #pragma unroll
    for (int i = 0; i < 4; ++i)
      a[i] = *(const short8*)(wp + ((ks*8 + nhalf*4 + i)*64 + lane)*8);
    const int pb = ((ks*4 + q) ^ l15) * 8;
    short8 b[4];
    #pragma unroll
    for (int j = 0; j < 4; ++j)
      b[j] = *(const short8*)(act + (ehalf*64 + j*16 + l15)*128 + pb);
    #pragma unroll
    for (int i = 0; i < 4; ++i)
      #pragma unroll
      for (int j = 0; j < 4; ++j)
        acc[i][j] = mfma_(a[i], b[j], acc[i][j]);
  }
}

static __device__ __forceinline__ void epi_bias_silu_store(f32x4 acc[4][4], const float* bias,
    u16* dst, int lane, int nhalf, int ehalf){
  const int l15 = lane & 15, q = lane >> 4;
  #pragma unroll
  for (int i = 0; i < 4; ++i){
    const int n0 = nhalf*64 + i*16 + q*4;
    f32x4 b = *(const f32x4*)(bias + n0);
    #pragma unroll
    for (int j = 0; j < 4; ++j){
      const int e = ehalf*64 + j*16 + l15;
      f32x4 v = acc[i][j] + b; silu4(v);
      store_pack(dst, e, n0, v);
    }
  }
}
static __device__ __forceinline__ void epi_res_add(f32x4 acc[4][4], const float* bias,
    u16* P, int lane, int nhalf, int ehalf){
  const int l15 = lane & 15, q = lane >> 4;
  #pragma unroll
  for (int i = 0; i < 4; ++i){
    const int n0 = nhalf*64 + i*16 + q*4;
    f32x4 b = *(const f32x4*)(bias + n0);
    #pragma unroll
    for (int j = 0; j < 4; ++j){
      const int e = ehalf*64 + j*16 + l15;
      f32x4 v = acc[i][j] + b; silu4(v);
      f32x4 p = load_pack(P, e, n0);
      store_pack(P, e, n0, p + v);
    }
  }
}

// ======================= prep: pack weights to bf16 A-frag layout =======================
struct PrepArgs {
  const float* src[14];
  int dst[14];
  int N[14], K[14];
  int cum[15];
};
__global__ void kPrep(PrepArgs pa, u16* __restrict__ wsU){
  int u = blockIdx.x*256 + threadIdx.x;
  if (u >= pa.cum[14]) return;
  int w = 0;
  #pragma unroll
  for (int i = 0; i < 14; ++i) if (u >= pa.cum[i+1]) w = i + 1;
  int f = u - pa.cum[w];
  int lane = f & 63, frag = f >> 6;
  int N = pa.N[w], K = pa.K[w];
  int ntiles = (N + 15) >> 4;
  int ks = frag / ntiles, nt = frag - ks*ntiles;
  int n  = nt*16 + (lane & 15);
  int k0 = ks*32 + ((lane >> 4) << 3);
  const float* src = pa.src[w];
  short8 o;
  #pragma unroll
  for (int j = 0; j < 8; ++j){
    int k = k0 + j;
    float v = (n < N && k < K) ? src[n*K + k] : 0.f;
    o[j] = (short)f2bf(v);
  }
  *(short8*)(wsU + (long)pa.dst[w] + (long)frag*512 + lane*8) = o;
}

// ======================= A1: xp4d = silu((silu(x1@w_p4^T+b)*sbf) @ w_down^T) =============
__global__ __launch_bounds__(256, 2) void kA1(
    const float* __restrict__ x1, const float* __restrict__ sbf0, const float* __restrict__ b_p4,
    const u16* __restrict__ wsU, u16* __restrict__ xp4d)
{
  __shared__ alignas(16) u16 X[128*128];
  __shared__ alignas(16) u16 P[128*128];
  const int tid = threadIdx.x, lane = tid & 63, wave = tid >> 6;
  const int nhalf = wave >> 1, ehalf = wave & 1;
  const int l15 = lane & 15, q = lane >> 4;
  const long e0 = (long)blockIdx.x * 128;

  { // zero P (pad trick) + stage x1 -> X
    short8 zz = {0,0,0,0,0,0,0,0};
    #pragma unroll
    for (int it = 0; it < 16; ++it)
      *(short8*)(P + (it*256 + tid)*8) = zz;
    const int c = tid & 31, r = tid >> 5;
    #pragma unroll
    for (int it = 0; it < 16; ++it){
      int e = r + it*8;
      f32x4 v = *(const f32x4*)(x1 + (e0 + e)*128 + c*4);
      store_pack(X, e, c*4, v);
    }
  }
  __syncthreads();

  f32x4 t[4][4]; zero44(t);
  gemm44<4>(wsU + WP4_O, X, lane, nhalf, ehalf, t);
  { // bias + silu, keep in regs
    #pragma unroll
    for (int i = 0; i < 4; ++i){
      int n0 = nhalf*64 + i*16 + q*4;
      f32x4 b = *(const f32x4*)(b_p4 + n0);
      #pragma unroll
      for (int j = 0; j < 4; ++j){ f32x4 v = t[i][j] + b; silu4(v); t[i][j] = v; }
    }
  }
  __syncthreads();  // everyone done reading X

  { // stage sbf0 -> X (k 0..41, zero 42..63)
    const int c = tid & 15, r = tid >> 4;
    #pragma unroll
    for (int it = 0; it < 8; ++it){
      int e = r + it*16;
      const float* sp = sbf0 + (e0 + e)*42;
      f32x4 v;
      if (c < 10){ float2 aa = *(const float2*)(sp + c*4); float2 bb = *(const float2*)(sp + c*4 + 2); v = (f32x4){aa.x, aa.y, bb.x, bb.y}; }
      else if (c == 10){ float2 aa = *(const float2*)(sp + 40); v = (f32x4){aa.x, aa.y, 0.f, 0.f}; }
      else v = (f32x4){0.f,0.f,0.f,0.f};
      store_pack(X, e, c*4, v);
    }
  }
  __syncthreads();

  { // s1v = sbf0 @ w_sbf1^T  -> P (n 0..15; rows>=8 zero by prep)
    f32x4 s0 = {0.f,0.f,0.f,0.f}, s1 = {0.f,0.f,0.f,0.f};
    #pragma unroll
    for (int ks = 0; ks < 2; ++ks){
      short8 a = *(const short8*)(wsU + WSBF1_O + (ks*64 + lane)*8);
      int pb = ((ks*4 + q) ^ l15) * 8;
      short8 b0 = *(const short8*)(X + (wave*32 + l15)*128 + pb);
      short8 b1 = *(const short8*)(X + (wave*32 + 16 + l15)*128 + pb);
      s0 = mfma_(a, b0, s0); s1 = mfma_(a, b1, s1);
    }
    store_pack(P, wave*32 + l15,      q*4, s0);
    store_pack(P, wave*32 + 16 + l15, q*4, s1);
  }
  __syncthreads();

  f32x4 sb[4][4]; zero44(sb);
  gemm44<1>(wsU + WSBF2_O, P, lane, nhalf, ehalf, sb);
  { // x_p4 = t * sbf -> X
    #pragma unroll
    for (int i = 0; i < 4; ++i){
      int n0 = nhalf*64 + i*16 + q*4;
      #pragma unroll
      for (int j = 0; j < 4; ++j){
        int e = ehalf*64 + j*16 + l15;
        store_pack(X, e, n0, t[i][j] * sb[i][j]);
      }
    }
  }
  __syncthreads();

  { // down: N=64
    const int np_ = wave & 1, ep_ = wave >> 1;
    f32x4 d[2][4];
    #pragma unroll
    for (int i = 0; i < 2; ++i)
      #pragma unroll
      for (int j = 0; j < 4; ++j) d[i][j] = (f32x4){0.f,0.f,0.f,0.f};
    #pragma unroll
    for (int ks = 0; ks < 4; ++ks){
      short8 a0 = *(const short8*)(wsU + WDOWN_O + ((ks*4 + np_*2 + 0)*64 + lane)*8);
      short8 a1 = *(const short8*)(wsU + WDOWN_O + ((ks*4 + np_*2 + 1)*64 + lane)*8);
      int pb = ((ks*4 + q) ^ l15) * 8;
      #pragma unroll
      for (int j = 0; j < 4; ++j){
        short8 b = *(const short8*)(X + (ep_*64 + j*16 + l15)*128 + pb);
        d[0][j] = mfma_(a0, b, d[0][j]);
        d[1][j] = mfma_(a1, b, d[1][j]);
      }
    }
    __syncthreads(); // all waves done reading X before P overwritten? (P free; just order)
    #pragma unroll
    for (int i = 0; i < 2; ++i){
      int n0 = np_*32 + i*16 + q*4;
      #pragma unroll
      for (int j = 0; j < 4; ++j){
        int e = ep_*64 + j*16 + l15;
        f32x4 v = d[i][j]; silu4(v);
        store_pack(P, e, n0, v);
      }
    }
  }
  __syncthreads();

  { // flush xp4d (bf16 raw copy, unswizzle)
    const int c = tid & 15, r = tid >> 4;
    #pragma unroll
    for (int it = 0; it < 8; ++it){
      int e = r + it*16;
      int phys = ((c >> 1) ^ (e & 15));
      short4v s = *(const short4v*)(P + e*128 + phys*8 + (c & 1)*4);
      *(short4v*)(xp4d + (e0 + e)*64 + c*4) = s;
    }
  }
}

// ======================= A2: ta_p = (ta @ w_t1^T) @ w_t2^T ==============================
__global__ __launch_bounds__(256) void kA2(
    const float* __restrict__ ta, const float* __restrict__ w_t1, const float* __restrict__ w_t2,
    u16* __restrict__ tap, int nwaves)
{
  const int tid = threadIdx.x, lane = tid & 63;
  const int half = lane >> 5, l31 = lane & 31;
  const int gw = blockIdx.x*4 + (tid >> 6);
  float wt1[10][8];
  #pragma unroll
  for (int c = 0; c < 10; ++c){
    int k = c*32 + l31;
    #pragma unroll
    for (int j = 0; j < 8; ++j)
      wt1[c][j] = (k < 294) ? w_t1[j*294 + k] : 0.f;
  }
  float w2a[8], w2b[8];
  #pragma unroll
  for (int j = 0; j < 8; ++j){ w2a[j] = w_t2[l31*8 + j]; w2b[j] = w_t2[(l31 + 32)*8 + j]; }

  for (long p = gw; p < 200000; p += nwaves){
    const long row = p*2 + half;
    const float* tr = ta + row*294;
    float acc[8];
    #pragma unroll
    for (int j = 0; j < 8; ++j) acc[j] = 0.f;
    #pragma unroll
    for (int c = 0; c < 9; ++c){
      float v = tr[c*32 + l31];
      #pragma unroll
      for (int j = 0; j < 8; ++j) acc[j] = fmaf(v, wt1[c][j], acc[j]);
    }
    if (l31 < 6){
      float v = tr[288 + l31];
      #pragma unroll
      for (int j = 0; j < 8; ++j) acc[j] = fmaf(v, wt1[9][j], acc[j]);
    }
    #pragma unroll
    for (int m = 16; m >= 1; m >>= 1)
      #pragma unroll
      for (int j = 0; j < 8; ++j)
        acc[j] += __shfl_xor(acc[j], m, 64);
    float o1 = 0.f, o2 = 0.f;
    #pragma unroll
    for (int j = 0; j < 8; ++j){ o1 = fmaf(acc[j], w2a[j], o1); o2 = fmaf(acc[j], w2b[j], o2); }
    tap[row*64 + l31]      = f2bf(o1);
    tap[row*64 + l31 + 32] = f2bf(o2);
  }
}

// ======================= B: gather, w_up, residual chain, p2 ============================
__global__ __launch_bounds__(256, 2) void kB(
    const float* __restrict__ x1, const float* __restrict__ sbf0, const int* __restrict__ pidx,
    const float* __restrict__ b_p2, const float* __restrict__ rbb1, const float* __restrict__ rbb2,
    const float* __restrict__ b_lin, const float* __restrict__ rab1, const float* __restrict__ rab2,
    const u16* __restrict__ wsU, const u16* __restrict__ xp4d, const u16* __restrict__ tap,
    float* __restrict__ out)
{
  __shared__ alignas(16) u16 X[128*128];
  __shared__ alignas(16) u16 P[128*128];
  __shared__ int IDX[128];
  const int tid = threadIdx.x, lane = tid & 63, wave = tid >> 6;
  const int nhalf = wave >> 1, ehalf = wave & 1;
  const int l15 = lane & 15, q = lane >> 4;
  const long e0 = (long)blockIdx.x * 128;

  { // stage x1 -> X ; load idx
    const int c = tid & 31, r = tid >> 5;
    #pragma unroll
    for (int it = 0; it < 16; ++it){
      int e = r + it*8;
      f32x4 v = *(const f32x4*)(x1 + (e0 + e)*128 + c*4);
      store_pack(X, e, c*4, v);
    }
    if (tid < 128) IDX[tid] = pidx[e0 + tid];
  }
  __syncthreads();

  f32x4 acc[4][4];

  // ---- s1: t0 = silu(x1 @ w_p2^T + b_p2) -> P
  zero44(acc);
  gemm44<4>(wsU + WP2_O, X, lane, nhalf, ehalf, acc);
  epi_bias_silu_store(acc, b_p2, P, lane, nhalf, ehalf);
  __syncthreads();

  // ---- gather: g = xp4d[idx[e]] * tap[e] -> X
  {
    const int el = tid >> 1, hf = tid & 1;
    const long row = IDX[el];
    #pragma unroll
    for (int cc = 0; cc < 4; ++cc){
      short8 av = *(const short8*)(xp4d + row*64 + hf*32 + cc*8);
      short8 bv = *(const short8*)(tap + (e0 + el)*64 + hf*32 + cc*8);
      f32x4 p0, p1v;
      #pragma unroll
      for (int m = 0; m < 4; ++m){
        p0[m]  = bf2f((u16)av[m])   * bf2f((u16)bv[m]);
        p1v[m] = bf2f((u16)av[4+m]) * bf2f((u16)bv[4+m]);
      }
      store_pack(X, el, hf*32 + cc*8,     p0);
      store_pack(X, el, hf*32 + cc*8 + 4, p1v);
    }
  }
  __syncthreads();

  // ---- s2: u = silu(g @ w_up^T); p = t0 + u  (RMW P)
  zero44(acc);
  gemm44<2>(wsU + WUP_O, X, lane, nhalf, ehalf, acc);
  {
    #pragma unroll
    for (int i = 0; i < 4; ++i){
      const int n0 = nhalf*64 + i*16 + q*4;
      #pragma unroll
      for (int j = 0; j < 4; ++j){
        const int e = ehalf*64 + j*16 + l15;
        f32x4 v = acc[i][j]; silu4(v);
        f32x4 p = load_pack(P, e, n0);
        store_pack(P, e, n0, p + v);
      }
    }
  }
  __syncthreads();

  // ---- res-before (NB=1): h1 = silu(p@rb1+b) -> X ; p += silu(h1@rb2+b)
  zero44(acc);
  gemm44<4>(wsU + RB1_O, P, lane, nhalf, ehalf, acc);
  epi_bias_silu_store(acc, rbb1, X, lane, nhalf, ehalf);
  __syncthreads();
  zero44(acc);
  gemm44<4>(wsU + RB2_O, X, lane, nhalf, ehalf, acc);
  epi_res_add(acc, rbb2, P, lane, nhalf, ehalf);
  __syncthreads();

  // ---- lin: p = silu(p@w_lin+b) + x1   (in-place: barrier between k-loop and writes)
  zero44(acc);
  gemm44<4>(wsU + WLIN_O, P, lane, nhalf, ehalf, acc);
  __syncthreads();
  {
    #pragma unroll
    for (int i = 0; i < 4; ++i){
      const int n0 = nhalf*64 + i*16 + q*4;
      f32x4 b = *(const f32x4*)(b_lin + n0);
      #pragma unroll
      for (int j = 0; j < 4; ++j){
        const int e = ehalf*64 + j*16 + l15;
        f32x4 v = acc[i][j] + b; silu4(v);
        f32x4 xv = *(const f32x4*)(x1 + (e0 + e)*128 + n0);
        store_pack(P, e, n0, v + xv);
      }
    }
  }
  __syncthreads();

  // ---- res-after x2
  #pragma unroll
  for (int rr = 0; rr < 2; ++rr){
    const u16* w1 = wsU + (rr ? RA11_O : RA10_O);
    const u16* w2 = wsU + (rr ? RA21_O : RA20_O);
    const float* bb1 = rab1 + rr*128;
    const float* bb2 = rab2 + rr*128;
    zero44(acc);
    gemm44<4>(w1, P, lane, nhalf, ehalf, acc);
    epi_bias_silu_store(acc, bb1, X, lane, nhalf, ehalf);
    __syncthreads();
    zero44(acc);
    gemm44<4>(w2, X, lane, nhalf, ehalf, acc);
    epi_res_add(acc, bb2, P, lane, nhalf, ehalf);
    __syncthreads();
  }

  // ---- flush p1 (f32) + stage sbf0 -> X
  {
    const int c = tid & 15, r = tid >> 4;
    #pragma unroll
    for (int it = 0; it < 8; ++it){
      int e = r + it*16;
      const float* sp = sbf0 + (e0 + e)*42;
      f32x4 v;
      if (c < 10){ float2 aa = *(const float2*)(sp + c*4); float2 bb = *(const float2*)(sp + c*4 + 2); v = (f32x4){aa.x, aa.y, bb.x, bb.y}; }
      else if (c == 10){ float2 aa = *(const float2*)(sp + 40); v = (f32x4){aa.x, aa.y, 0.f, 0.f}; }
      else v = (f32x4){0.f,0.f,0.f,0.f};
      store_pack(X, e, c*4, v);
    }
    const int c2 = tid & 31, r2 = tid >> 5;
    #pragma unroll
    for (int it = 0; it < 16; ++it){
      int e = r2 + it*8;
      f32x4 v = load_pack(P, e, c2*4);
      *(f32x4*)(out + (e0 + e)*128 + c2*4) = v;
    }
  }
  __syncthreads();

  // ---- s7: p2 = (sbf0 @ w_sbf^T) * p1  (RMW P, then flush)
  zero44(acc);
  gemm44<2>(wsU + WSBF_O, X, lane, nhalf, ehalf, acc);
  {
    #pragma unroll
    for (int i = 0; i < 4; ++i){
      const int n0 = nhalf*64 + i*16 + q*4;
      #pragma unroll
      for (int j = 0; j < 4; ++j){
        const int e = ehalf*64 + j*16 + l15;
        f32x4 p = load_pack(P, e, n0);
        store_pack(P, e, n0, acc[i][j] * p);
      }
    }
  }
  __syncthreads();
  {
    const int c2 = tid & 31, r2 = tid >> 5;
    #pragma unroll
    for (int it = 0; it < 16; ++it){
      int e = r2 + it*8;
      f32x4 v = load_pack(P, e, c2*4);
      *(f32x4*)(out + 51200000L + (e0 + e)*128 + c2*4) = v;
    }
  }
}

// ======================= launch =======================
extern "C" void kernel_launch(void* const* d_in, const int* in_sizes, int n_in,
                              void* d_out, int out_size, void* d_ws, size_t ws_size,
                              hipStream_t stream) {
  const float* x1     = (const float*)d_in[0];
  const float* sbf0   = (const float*)d_in[1];
  const float* ta     = (const float*)d_in[2];
  const int*   pidx   = (const int*)d_in[3];
  const float* w_p2   = (const float*)d_in[4];
  const float* b_p2   = (const float*)d_in[5];
  const float* w_p4   = (const float*)d_in[6];
  const float* b_p4   = (const float*)d_in[7];
  const float* w_sbf1 = (const float*)d_in[8];
  const float* w_sbf2 = (const float*)d_in[9];
  const float* w_t1   = (const float*)d_in[10];
  const float* w_t2   = (const float*)d_in[11];
  const float* w_down = (const float*)d_in[12];
  const float* w_up   = (const float*)d_in[13];
  const float* rb_w1  = (const float*)d_in[14];
  const float* rb_b1  = (const float*)d_in[15];
  const float* rb_w2  = (const float*)d_in[16];
  const float* rb_b2  = (const float*)d_in[17];
  const float* w_lin  = (const float*)d_in[18];
  const float* b_lin  = (const float*)d_in[19];
  const float* ra_w1  = (const float*)d_in[20];
  const float* ra_b1  = (const float*)d_in[21];
  const float* ra_w2  = (const float*)d_in[22];
  const float* ra_b2  = (const float*)d_in[23];
  const float* w_sbf  = (const float*)d_in[24];

  u16* wsU = (u16*)d_ws;

  PrepArgs pa;
  const float* srcs[14] = {w_p2, w_p4, w_up, w_down, w_sbf, w_sbf1, w_sbf2,
                           rb_w1, rb_w2, w_lin, ra_w1, ra_w2, ra_w1 + 16384, ra_w2 + 16384};
  const int dsts[14] = {WP2_O, WP4_O, WUP_O, WDOWN_O, WSBF_O, WSBF1_O, WSBF2_O,
                        RB1_O, RB2_O, WLIN_O, RA10_O, RA20_O, RA11_O, RA21_O};
  const int Ns[14]  = {128,128,128, 64,128,  8,128,128,128,128,128,128,128,128};
  const int Ks[14]  = {128,128, 64,128, 42, 42,  8,128,128,128,128,128,128,128};
  const int Kps[14] = {128,128, 64,128, 64, 64, 32,128,128,128,128,128,128,128};
  int cum = 0; pa.cum[0] = 0;
  for (int i = 0; i < 14; ++i){
    int ntiles = (Ns[i] + 15) / 16;
    cum += (Kps[i]/32) * ntiles * 64;
    pa.cum[i+1] = cum;
    pa.src[i] = srcs[i]; pa.dst[i] = dsts[i]; pa.N[i] = Ns[i]; pa.K[i] = Ks[i];
  }
  hipLaunchKernelGGL(kPrep, dim3((cum + 255)/256), dim3(256), 0, stream, pa, wsU);
  hipLaunchKernelGGL(kA1, dim3(3125), dim3(256), 0, stream, x1, sbf0, b_p4, (const u16*)wsU, wsU + XP4D_O);
  hipLaunchKernelGGL(kA2, dim3(2048), dim3(256), 0, stream, ta, w_t1, w_t2, wsU + TAP_O, 2048*4);
  hipLaunchKernelGGL(kB, dim3(3125), dim3(256), 0, stream,
                     x1, sbf0, pidx, b_p2, rb_b1, rb_b2, b_lin, ra_b1, ra_b2,
                     (const u16*)wsU, (const u16*)(wsU + XP4D_O), (const u16*)(wsU + TAP_O),
                     (float*)d_out);
}